// Round 6
// baseline (945.692 us; speedup 1.0000x reference)
//
#include <hip/hip_runtime.h>
#include <hip/hip_bf16.h>
#include <math.h>

#define B 8
#define T_MEL 400
#define N_MEL 80
#define L_TXT 128
#define D_TXT 512
#define E 256
#define HID 256
#define EMB 128
#define N_SPK 100
#define HH 128

// ---- workspace layout (float element offsets) ----
#define OFF_W      0
#define OFF_C      256
#define OFF_WXT    272
#define OFF_WQT    (OFF_WXT + N_MEL*E)        // 20752
#define OFF_WIHT   (OFF_WQT + D_TXT*E)        // 151824
#define OFF_BSUM   (OFF_WIHT + 2*2*256*512)   // 676112
#define OFF_X1     (OFF_BSUM + 2048)          // 678160
#define OFF_Q1     (OFF_X1 + B*T_MEL*E)       // 1497360
#define OFF_G      OFF_X1                      // gates overlay x1+q1 (dead by then)
#define OFF_H0     (OFF_Q1 + B*L_TXT*E)       // 1759504
#define OFF_O1     (OFF_H0 + B*L_TXT*E)       // 2021648
#define OFF_O2     (OFF_O1 + B*L_TXT*HID)     // 2283792

typedef __attribute__((ext_vector_type(8))) short short8v;  // 8 bf16 (4 VGPRs)
typedef __attribute__((ext_vector_type(4))) float f32x4;

__device__ __forceinline__ float fast_sigmoid(float x){ return 1.f/(1.f+__expf(-x)); }
__device__ __forceinline__ float fast_tanh(float x){ float e=__expf(2.f*x); return 1.f - 2.f/(e+1.f); }
__device__ __forceinline__ short bf16b(float f){
  union { __hip_bfloat16 b; short s; } u; u.b = __float2bfloat16(f); return u.s;
}

// ---- prep: w = Wout^T v, c = bout.v ; transposes WxT, WqT, WihT ; bias sums ----
__global__ void k_prep(const float* __restrict__ Wout, const float* __restrict__ bout,
                       const float* __restrict__ v,    const float* __restrict__ Wx,
                       const float* __restrict__ Wq,   const float* __restrict__ wih,
                       const float* __restrict__ bih,  const float* __restrict__ bhh,
                       float* __restrict__ ws){
  int blk = blockIdx.x, tid = threadIdx.x;
  if (blk == 0){
    float acc = 0.f;
    for (int j=0;j<E;j++) acc += Wout[j*E + tid] * v[j];
    ws[OFF_W + tid] = acc;
    if (tid==0){ float c=0.f; for(int j=0;j<E;j++) c += bout[j]*v[j]; ws[OFF_C]=c; }
  } else if (blk <= N_MEL){
    int m = blk-1;
    ws[OFF_WXT + m*E + tid] = Wx[tid*N_MEL + m];
  } else if (blk <= N_MEL + D_TXT){
    int k = blk-1-N_MEL;
    ws[OFF_WQT + k*E + tid] = Wq[tid*D_TXT + k];
  } else if (blk <= N_MEL + D_TXT + 1024){
    int idx = blk-1-N_MEL-D_TXT;      // ld*256 + k
    int ld = idx >> 8, k = idx & 255;
    for (int g = tid; g < 512; g += 256)
      ws[OFF_WIHT + idx*512 + g] = wih[(ld*512+g)*256 + k];
  } else {
    for (int i = tid; i < 2048; i += 256)
      ws[OFF_BSUM + i] = bih[i] + bhh[i];
  }
}

// ---- x1[b,t,e] = sum_m x[b,m,t]*Wx[e,m] + bx[e] ; t-tile 4 ----
__global__ __launch_bounds__(256) void k_x1(const float* __restrict__ x,
                                            const float* __restrict__ bx,
                                            float* __restrict__ ws){
  int blk = blockIdx.x; int b = blk/100; int t0 = (blk%100)*4; int tid = threadIdx.x;
  __shared__ float sx[N_MEL][4];
  for (int i = tid; i < N_MEL*4; i += 256){
    int m = i>>2, ii = i&3;
    sx[m][ii] = x[(b*N_MEL+m)*T_MEL + t0 + ii];
  }
  __syncthreads();
  float bxe = bx[tid];
  float a0=bxe,a1=bxe,a2=bxe,a3=bxe;
  const float* wxt = ws + OFF_WXT;
  #pragma unroll 4
  for (int m=0;m<N_MEL;m++){
    float w = wxt[m*E + tid];
    a0 += sx[m][0]*w; a1 += sx[m][1]*w; a2 += sx[m][2]*w; a3 += sx[m][3]*w;
  }
  float* x1 = ws + OFF_X1 + (b*T_MEL + t0)*E + tid;
  x1[0]=a0; x1[E]=a1; x1[2*E]=a2; x1[3*E]=a3;
}

// ---- q1[b,l,e] = sum_d text[b,l,d]*Wq[e,d] + bq[e] ; l-tile 4 ----
__global__ __launch_bounds__(256) void k_q1(const float* __restrict__ text,
                                            const float* __restrict__ bq,
                                            float* __restrict__ ws){
  int blk = blockIdx.x; int b = blk/32; int l0 = (blk%32)*4; int tid = threadIdx.x;
  __shared__ float st[4][D_TXT];
  for (int i = tid; i < 4*D_TXT; i += 256){
    int li = i / D_TXT, k = i % D_TXT;
    st[li][k] = text[(b*L_TXT + l0 + li)*D_TXT + k];
  }
  __syncthreads();
  float bqe = bq[tid];
  float a0=bqe,a1=bqe,a2=bqe,a3=bqe;
  const float* wqt = ws + OFF_WQT;
  #pragma unroll 2
  for (int k=0;k<D_TXT;k++){
    float w = wqt[k*E + tid];
    a0 += st[0][k]*w; a1 += st[1][k]*w; a2 += st[2][k]*w; a3 += st[3][k]*w;
  }
  float* q1 = ws + OFF_Q1 + (b*L_TXT + l0)*E + tid;
  q1[0]=a0; q1[E]=a1; q1[2*E]=a2; q1[3*E]=a3;
}

// ---- scores + masked softmax + context + h0 ; one block per (b,l) ----
__global__ __launch_bounds__(256) void k_score(const int* __restrict__ mel_len,
                                               float* __restrict__ ws,
                                               float* __restrict__ d_out){
  int blk = blockIdx.x; int b = blk >> 7; int l = blk & 127;
  int tid = threadIdx.x; int lane = tid & 63; int wv = tid >> 6;
  __shared__ float sl[T_MEL];
  __shared__ float red[8];
  const float* x1 = ws + OFF_X1 + b*T_MEL*E;
  const float* q1 = ws + OFF_Q1 + (b*L_TXT+l)*E;
  float qv[4], wv4[4];
  #pragma unroll
  for (int j=0;j<4;j++){ qv[j] = q1[lane+64*j]; wv4[j] = ws[OFF_W + lane + 64*j]; }
  float cc = ws[OFF_C];
  int len = mel_len[b];
  for (int t = wv; t < T_MEL; t += 4){
    const float* xr = x1 + t*E;
    float s = 0.f;
    #pragma unroll
    for (int j=0;j<4;j++) s += wv4[j]*fast_tanh(xr[lane+64*j] + qv[j]);
    #pragma unroll
    for (int off=32; off>=1; off>>=1) s += __shfl_xor(s, off);
    if (lane==0) sl[t] = s + cc;
  }
  __syncthreads();
  float mx = -3.0e38f;
  for (int t = tid; t < T_MEL; t += 256) if (t < len) mx = fmaxf(mx, sl[t]);
  #pragma unroll
  for (int off=32; off>=1; off>>=1) mx = fmaxf(mx, __shfl_xor(mx, off));
  if (lane==0) red[wv] = mx;
  __syncthreads();
  mx = fmaxf(fmaxf(red[0],red[1]),fmaxf(red[2],red[3]));
  float se = 0.f;
  for (int t = tid; t < T_MEL; t += 256){
    float p = (t < len) ? __expf(sl[t]-mx) : 0.f;
    sl[t] = p; se += p;
  }
  #pragma unroll
  for (int off=32; off>=1; off>>=1) se += __shfl_xor(se, off);
  if (lane==0) red[4+wv] = se;
  __syncthreads();
  float rsum = 1.f/(red[4]+red[5]+red[6]+red[7]);
  float* sc_out = d_out + 1824 + (b*L_TXT + l)*T_MEL;
  for (int t = tid; t < T_MEL; t += 256){
    float p = sl[t]*rsum;
    sl[t] = p; sc_out[t] = p;
  }
  __syncthreads();
  float a = 0.f;
  int e = tid;
  #pragma unroll 4
  for (int t = 0; t < len; t++) a += sl[t]*x1[t*E + e];
  ws[OFF_H0 + (b*L_TXT+l)*E + e] = q1[e] + a;
}

// ---- gates_in: gathered_in[b,row(t),:] @ WihT + (bih+bhh) ; t-tile 8
//      output layout: [b,dir][t][unit*4 + gate]  (gate 0:i 1:f 2:g 3:o) ----
__global__ __launch_bounds__(512) void k_gates(const float* __restrict__ in,
                                               const int* __restrict__ txt_len,
                                               float* __restrict__ gates, int layer,
                                               float* __restrict__ ws){
  int idx = blockIdx.x; int tt = idx & 15; int dir = (idx>>4)&1; int b = idx>>5;
  int tid = threadIdx.x;
  __shared__ float si[8][HID];
  int len = txt_len[b];
  for (int i = tid; i < 8*HID; i += 512){
    int r = i >> 8, k = i & 255;
    int t = tt*8 + r;
    int row = dir ? max(0, len-1-t) : t;
    si[r][k] = in[(b*L_TXT + row)*HID + k];
  }
  __syncthreads();
  int ld = layer*2 + dir;
  int g = tid;
  float bsum = ws[OFF_BSUM + ld*512 + g];
  float acc[8];
  #pragma unroll
  for (int r=0;r<8;r++) acc[r] = bsum;
  const float* wt = ws + OFF_WIHT + ld*256*512;
  for (int k=0;k<HID;k++){
    float w = wt[k*512 + g];
    #pragma unroll
    for (int r=0;r<8;r++) acc[r] += si[r][k]*w;
  }
  float* go = gates + ((b*2+dir)*L_TXT + tt*8)*512 + (g&127)*4 + (g>>7);
  #pragma unroll
  for (int r=0;r<8;r++) go[r*512] = acc[r];
}

// ---- recurrent scan v6 (MFMA) ; one block per (b,dir) ; 512 thr = 8 waves
//      Whh held as 16 named bf16 A-fragments/lane (64 VGPR); per step:
//      16x mfma_f32_16x16x32_bf16, in-wave activations (C-rows = all 4 gates of
//      the wave's 16 units), 1 barrier/step, double-buffered bf16 h in LDS. ----
__global__ __launch_bounds__(512, 1) void k_scan(const float* __restrict__ gates,
                                                 const float* __restrict__ whh_all,
                                                 const int* __restrict__ txt_len,
                                                 float* __restrict__ out, int layer){
  int dir = blockIdx.x & 1; int b = blockIdx.x >> 1;
  int tid = threadIdx.x;
  int w    = tid >> 6;       // wave 0..7
  int lane = tid & 63;
  int r16  = lane & 15;      // A-row within M-tile / C-col
  int h4   = lane >> 4;      // k-subgroup / C-row group
  __shared__ ushort h_lds[2][HH];                   // double-buffered h (bf16)
  __shared__ __align__(16) float h_hist[160][HH];   // 80KB -> forces 1 block/CU

  // A-fragments: wave w owns M-tiles {w, w+8, w+16, w+24} = gates i,f,g,o of units 16w..16w+15
  // fragment (mi,t): lane holds Whh[16*(w+8*mi)+r16][32*t+8*h4 + j], j=0..7
  const float* wb = whh_all + (size_t)(layer*2+dir)*512*HH;
  #define LDA(mi,t) ({ const float* rp_ = wb + (size_t)(16*(w+8*(mi)) + r16)*HH + 32*(t) + 8*h4; \
      float4 p0_ = *(const float4*)rp_; float4 p1_ = *(const float4*)(rp_+4); \
      short8v f_ = { bf16b(p0_.x),bf16b(p0_.y),bf16b(p0_.z),bf16b(p0_.w), \
                     bf16b(p1_.x),bf16b(p1_.y),bf16b(p1_.z),bf16b(p1_.w) }; f_; })
  short8v a00=LDA(0,0), a01=LDA(0,1), a02=LDA(0,2), a03=LDA(0,3);
  short8v a10=LDA(1,0), a11=LDA(1,1), a12=LDA(1,2), a13=LDA(1,3);
  short8v a20=LDA(2,0), a21=LDA(2,1), a22=LDA(2,2), a23=LDA(2,3);
  short8v a30=LDA(3,0), a31=LDA(3,1), a32=LDA(3,2), a33=LDA(3,3);
  #undef LDA

  if (tid < HH) h_lds[0][tid] = 0;   // h_{-1} = 0 (bf16 zero bits)
  int len = txt_len[b];
  // gate-input pointer: this lane's 4 units are u0..u0+3, 4 gates each (i,f,g,o)
  int u0 = 16*w + 4*h4;
  const float* gb = gates + (size_t)(b*2+dir)*L_TXT*512 + u0*4;
  float4 q0 = *(const float4*)(gb);    float4 q1 = *(const float4*)(gb+4);
  float4 q2 = *(const float4*)(gb+8);  float4 q3 = *(const float4*)(gb+12);
  float c0=0.f, c1=0.f, c2=0.f, c3=0.f;
  __syncthreads();

  for (int s=0; s<L_TXT; s++){
    // B-fragments: every lane loads the same h k-slice (broadcast, 4 addrs/wave)
    const ushort* hb = h_lds[s&1];
    short8v b0 = *(const short8v*)&hb[     8*h4];
    short8v b1 = *(const short8v*)&hb[32 + 8*h4];
    short8v b2 = *(const short8v*)&hb[64 + 8*h4];
    short8v b3 = *(const short8v*)&hb[96 + 8*h4];
    f32x4 acc0 = {0.f,0.f,0.f,0.f}, acc1 = acc0, acc2 = acc0, acc3 = acc0;
    acc0 = __builtin_amdgcn_mfma_f32_16x16x32_bf16(a00,b0,acc0,0,0,0);
    acc1 = __builtin_amdgcn_mfma_f32_16x16x32_bf16(a10,b0,acc1,0,0,0);
    acc2 = __builtin_amdgcn_mfma_f32_16x16x32_bf16(a20,b0,acc2,0,0,0);
    acc3 = __builtin_amdgcn_mfma_f32_16x16x32_bf16(a30,b0,acc3,0,0,0);
    acc0 = __builtin_amdgcn_mfma_f32_16x16x32_bf16(a01,b1,acc0,0,0,0);
    acc1 = __builtin_amdgcn_mfma_f32_16x16x32_bf16(a11,b1,acc1,0,0,0);
    acc2 = __builtin_amdgcn_mfma_f32_16x16x32_bf16(a21,b1,acc2,0,0,0);
    acc3 = __builtin_amdgcn_mfma_f32_16x16x32_bf16(a31,b1,acc3,0,0,0);
    acc0 = __builtin_amdgcn_mfma_f32_16x16x32_bf16(a02,b2,acc0,0,0,0);
    acc1 = __builtin_amdgcn_mfma_f32_16x16x32_bf16(a12,b2,acc1,0,0,0);
    acc2 = __builtin_amdgcn_mfma_f32_16x16x32_bf16(a22,b2,acc2,0,0,0);
    acc3 = __builtin_amdgcn_mfma_f32_16x16x32_bf16(a32,b2,acc3,0,0,0);
    acc0 = __builtin_amdgcn_mfma_f32_16x16x32_bf16(a03,b3,acc0,0,0,0);
    acc1 = __builtin_amdgcn_mfma_f32_16x16x32_bf16(a13,b3,acc1,0,0,0);
    acc2 = __builtin_amdgcn_mfma_f32_16x16x32_bf16(a23,b3,acc2,0,0,0);
    acc3 = __builtin_amdgcn_mfma_f32_16x16x32_bf16(a33,b3,acc3,0,0,0);
    // prefetch next step's gate inputs (used after the barrier)
    const float* gn = gb + (size_t)(s+1 < L_TXT ? s+1 : s)*512;
    float4 n0 = *(const float4*)(gn);    float4 n1 = *(const float4*)(gn+4);
    float4 n2 = *(const float4*)(gn+8);  float4 n3 = *(const float4*)(gn+12);
    // activations: acc_mi[j] = (Whh h)[gate mi, unit u0+j]; identical across r16 lanes
    float i_,f_,g_,o_, h0v,h1v,h2v,h3v;
    i_ = fast_sigmoid(acc0[0]+q0.x); f_ = fast_sigmoid(acc1[0]+q0.y);
    g_ = fast_tanh   (acc2[0]+q0.z); o_ = fast_sigmoid(acc3[0]+q0.w);
    c0 = f_*c0 + i_*g_; h0v = o_*fast_tanh(c0);
    i_ = fast_sigmoid(acc0[1]+q1.x); f_ = fast_sigmoid(acc1[1]+q1.y);
    g_ = fast_tanh   (acc2[1]+q1.z); o_ = fast_sigmoid(acc3[1]+q1.w);
    c1 = f_*c1 + i_*g_; h1v = o_*fast_tanh(c1);
    i_ = fast_sigmoid(acc0[2]+q2.x); f_ = fast_sigmoid(acc1[2]+q2.y);
    g_ = fast_tanh   (acc2[2]+q2.z); o_ = fast_sigmoid(acc3[2]+q2.w);
    c2 = f_*c2 + i_*g_; h2v = o_*fast_tanh(c2);
    i_ = fast_sigmoid(acc0[3]+q3.x); f_ = fast_sigmoid(acc1[3]+q3.y);
    g_ = fast_tanh   (acc2[3]+q3.z); o_ = fast_sigmoid(acc3[3]+q3.w);
    c3 = f_*c3 + i_*g_; h3v = o_*fast_tanh(c3);
    if (r16 == 0){
      uint lo = (uint)(ushort)bf16b(h0v) | ((uint)(ushort)bf16b(h1v) << 16);
      uint hi = (uint)(ushort)bf16b(h2v) | ((uint)(ushort)bf16b(h3v) << 16);
      *(uint2*)&h_lds[(s+1)&1][u0] = make_uint2(lo, hi);
      *(float4*)&h_hist[s][u0] = make_float4(h0v, h1v, h2v, h3v);
    }
    q0 = n0; q1 = n1; q2 = n2; q3 = n3;
    __syncthreads();
  }

  // write outputs once, coalesced; dir=1 applies pack-reverse semantics
  for (int idx = tid; idx < L_TXT*HH; idx += 512){
    int pos = idx >> 7; int uo = idx & 127;
    int src = dir ? (pos < len ? len-1-pos : 0) : pos;
    out[(size_t)(b*L_TXT+pos)*HID + dir*HH + uo] = h_hist[src][uo];
  }
}

// ---- masked mean pool + p1/tanh + normalize + p2 ----
__global__ __launch_bounds__(256) void k_final(const float* __restrict__ o2,
                                               const int* __restrict__ txt_len,
                                               const float* __restrict__ p1w,
                                               const float* __restrict__ p1b,
                                               const float* __restrict__ p2w,
                                               const float* __restrict__ p2b,
                                               float* __restrict__ d_out){
  int b = blockIdx.x; int tid = threadIdx.x;
  __shared__ float pl[HID];
  __shared__ float ol[EMB];
  __shared__ float nrm;
  int len = txt_len[b];
  float s = 0.f;
  for (int t=0; t<len; t++) s += o2[(b*L_TXT+t)*HID + tid];
  pl[tid] = s / (float)len;
  __syncthreads();
  if (tid < EMB){
    float a = p1b[tid];
    for (int k=0;k<HID;k++) a += pl[k]*p1w[tid*HID+k];
    ol[tid] = fast_tanh(a);
  }
  __syncthreads();
  if (tid == 0){
    float q = 0.f;
    for (int k=0;k<EMB;k++) q += ol[k]*ol[k];
    nrm = rsqrtf(q);
  }
  __syncthreads();
  if (tid < EMB) d_out[800 + b*EMB + tid] = ol[tid]*nrm;
  if (tid < N_SPK){
    float a = p2b[tid];
    for (int k=0;k<EMB;k++) a += ol[k]*p2w[tid*EMB+k];
    d_out[b*N_SPK + tid] = a;
  }
}

extern "C" void kernel_launch(void* const* d_in, const int* in_sizes, int n_in,
                              void* d_out, int out_size, void* d_ws, size_t ws_size,
                              hipStream_t stream) {
  const float* x       = (const float*)d_in[0];
  const int*   mel_len = (const int*)  d_in[1];
  const float* text    = (const float*)d_in[2];
  const int*   txt_len = (const int*)  d_in[3];
  const float* Wx      = (const float*)d_in[4];
  const float* bx      = (const float*)d_in[5];
  const float* Wq      = (const float*)d_in[6];
  const float* bq      = (const float*)d_in[7];
  const float* Wout    = (const float*)d_in[8];
  const float* bout    = (const float*)d_in[9];
  const float* v       = (const float*)d_in[10];
  const float* wih     = (const float*)d_in[11];
  const float* whh     = (const float*)d_in[12];
  const float* bih     = (const float*)d_in[13];
  const float* bhh     = (const float*)d_in[14];
  const float* p1w     = (const float*)d_in[15];
  const float* p1b     = (const float*)d_in[16];
  const float* p2w     = (const float*)d_in[17];
  const float* p2b     = (const float*)d_in[18];
  float* ws  = (float*)d_ws;
  float* out = (float*)d_out;

  k_prep<<<1618, 256, 0, stream>>>(Wout, bout, v, Wx, Wq, wih, bih, bhh, ws);
  k_x1  <<<800, 256, 0, stream>>>(x, bx, ws);
  k_q1  <<<256, 256, 0, stream>>>(text, bq, ws);
  k_score<<<1024, 256, 0, stream>>>(mel_len, ws, out);

  float* G = ws + OFF_G;
  k_gates<<<256, 512, 0, stream>>>(ws + OFF_H0, txt_len, G, 0, ws);
  k_scan <<<16, 512, 0, stream>>>(G, whh, txt_len, ws + OFF_O1, 0);
  k_gates<<<256, 512, 0, stream>>>(ws + OFF_O1, txt_len, G, 1, ws);
  k_scan <<<16, 512, 0, stream>>>(G, whh, txt_len, ws + OFF_O2, 1);

  k_final<<<8, 256, 0, stream>>>(ws + OFF_O2, txt_len, p1w, p1b, p2w, p2b, out);
}

// Round 7
// 724.323 us; speedup vs baseline: 1.3056x; 1.3056x over previous
//
#include <hip/hip_runtime.h>
#include <hip/hip_bf16.h>
#include <math.h>

#define B 8
#define T_MEL 400
#define N_MEL 80
#define L_TXT 128
#define D_TXT 512
#define E 256
#define HID 256
#define EMB 128
#define N_SPK 100
#define HH 128

// ---- workspace layout (float element offsets) ----
#define OFF_W      0
#define OFF_C      256
#define OFF_WXT    272
#define OFF_WQT    (OFF_WXT + N_MEL*E)        // 20752
#define OFF_WIHT   (OFF_WQT + D_TXT*E)        // 151824
#define OFF_BSUM   (OFF_WIHT + 2*2*256*512)   // 676112
#define OFF_X1     (OFF_BSUM + 2048)          // 678160
#define OFF_Q1     (OFF_X1 + B*T_MEL*E)       // 1497360
#define OFF_G      OFF_X1                      // gates overlay x1+q1 (dead by then); 1,048,576 <= 1,081,344
#define OFF_H0     (OFF_Q1 + B*L_TXT*E)       // 1759504
#define OFF_O1     (OFF_H0 + B*L_TXT*E)       // 2021648
#define OFF_O2     (OFF_O1 + B*L_TXT*HID)     // 2283792
#define OFF_HS0    OFF_H0                      // hseq layer0 overlays H0 (dead after k_gates0) ; 262144 floats exact
#define OFF_HS1    OFF_O1                      // hseq layer1 overlays O1 (dead after k_gates1) ; 262144 floats exact

typedef __attribute__((ext_vector_type(8))) short short8v;  // 8 bf16 (4 VGPRs)
typedef __attribute__((ext_vector_type(4))) float f32x4;

__device__ __forceinline__ float fast_sigmoid(float x){ return 1.f/(1.f+__expf(-x)); }
__device__ __forceinline__ float fast_tanh(float x){ float e=__expf(2.f*x); return 1.f - 2.f/(e+1.f); }
__device__ __forceinline__ short bf16b(float f){
  union { __hip_bfloat16 b; short s; } u; u.b = __float2bfloat16(f); return u.s;
}

// ---- prep: w = Wout^T v, c = bout.v ; transposes WxT, WqT, WihT ; bias sums ----
__global__ void k_prep(const float* __restrict__ Wout, const float* __restrict__ bout,
                       const float* __restrict__ v,    const float* __restrict__ Wx,
                       const float* __restrict__ Wq,   const float* __restrict__ wih,
                       const float* __restrict__ bih,  const float* __restrict__ bhh,
                       float* __restrict__ ws){
  int blk = blockIdx.x, tid = threadIdx.x;
  if (blk == 0){
    float acc = 0.f;
    for (int j=0;j<E;j++) acc += Wout[j*E + tid] * v[j];
    ws[OFF_W + tid] = acc;
    if (tid==0){ float c=0.f; for(int j=0;j<E;j++) c += bout[j]*v[j]; ws[OFF_C]=c; }
  } else if (blk <= N_MEL){
    int m = blk-1;
    ws[OFF_WXT + m*E + tid] = Wx[tid*N_MEL + m];
  } else if (blk <= N_MEL + D_TXT){
    int k = blk-1-N_MEL;
    ws[OFF_WQT + k*E + tid] = Wq[tid*D_TXT + k];
  } else if (blk <= N_MEL + D_TXT + 1024){
    int idx = blk-1-N_MEL-D_TXT;      // ld*256 + k
    int ld = idx >> 8, k = idx & 255;
    for (int g = tid; g < 512; g += 256)
      ws[OFF_WIHT + idx*512 + g] = wih[(ld*512+g)*256 + k];
  } else {
    for (int i = tid; i < 2048; i += 256)
      ws[OFF_BSUM + i] = bih[i] + bhh[i];
  }
}

// ---- x1[b,t,e] = sum_m x[b,m,t]*Wx[e,m] + bx[e] ; t-tile 4 ----
__global__ __launch_bounds__(256) void k_x1(const float* __restrict__ x,
                                            const float* __restrict__ bx,
                                            float* __restrict__ ws){
  int blk = blockIdx.x; int b = blk/100; int t0 = (blk%100)*4; int tid = threadIdx.x;
  __shared__ float sx[N_MEL][4];
  for (int i = tid; i < N_MEL*4; i += 256){
    int m = i>>2, ii = i&3;
    sx[m][ii] = x[(b*N_MEL+m)*T_MEL + t0 + ii];
  }
  __syncthreads();
  float bxe = bx[tid];
  float a0=bxe,a1=bxe,a2=bxe,a3=bxe;
  const float* wxt = ws + OFF_WXT;
  #pragma unroll 4
  for (int m=0;m<N_MEL;m++){
    float w = wxt[m*E + tid];
    a0 += sx[m][0]*w; a1 += sx[m][1]*w; a2 += sx[m][2]*w; a3 += sx[m][3]*w;
  }
  float* x1 = ws + OFF_X1 + (b*T_MEL + t0)*E + tid;
  x1[0]=a0; x1[E]=a1; x1[2*E]=a2; x1[3*E]=a3;
}

// ---- q1[b,l,e] = sum_d text[b,l,d]*Wq[e,d] + bq[e] ; l-tile 4 ----
__global__ __launch_bounds__(256) void k_q1(const float* __restrict__ text,
                                            const float* __restrict__ bq,
                                            float* __restrict__ ws){
  int blk = blockIdx.x; int b = blk/32; int l0 = (blk%32)*4; int tid = threadIdx.x;
  __shared__ float st[4][D_TXT];
  for (int i = tid; i < 4*D_TXT; i += 256){
    int li = i / D_TXT, k = i % D_TXT;
    st[li][k] = text[(b*L_TXT + l0 + li)*D_TXT + k];
  }
  __syncthreads();
  float bqe = bq[tid];
  float a0=bqe,a1=bqe,a2=bqe,a3=bqe;
  const float* wqt = ws + OFF_WQT;
  #pragma unroll 2
  for (int k=0;k<D_TXT;k++){
    float w = wqt[k*E + tid];
    a0 += st[0][k]*w; a1 += st[1][k]*w; a2 += st[2][k]*w; a3 += st[3][k]*w;
  }
  float* q1 = ws + OFF_Q1 + (b*L_TXT + l0)*E + tid;
  q1[0]=a0; q1[E]=a1; q1[2*E]=a2; q1[3*E]=a3;
}

// ---- scores + masked softmax + context + h0 ; one block per (b,l) ----
__global__ __launch_bounds__(256) void k_score(const int* __restrict__ mel_len,
                                               float* __restrict__ ws,
                                               float* __restrict__ d_out){
  int blk = blockIdx.x; int b = blk >> 7; int l = blk & 127;
  int tid = threadIdx.x; int lane = tid & 63; int wv = tid >> 6;
  __shared__ float sl[T_MEL];
  __shared__ float red[8];
  const float* x1 = ws + OFF_X1 + b*T_MEL*E;
  const float* q1 = ws + OFF_Q1 + (b*L_TXT+l)*E;
  float qv[4], wv4[4];
  #pragma unroll
  for (int j=0;j<4;j++){ qv[j] = q1[lane+64*j]; wv4[j] = ws[OFF_W + lane + 64*j]; }
  float cc = ws[OFF_C];
  int len = mel_len[b];
  for (int t = wv; t < T_MEL; t += 4){
    const float* xr = x1 + t*E;
    float s = 0.f;
    #pragma unroll
    for (int j=0;j<4;j++) s += wv4[j]*fast_tanh(xr[lane+64*j] + qv[j]);
    #pragma unroll
    for (int off=32; off>=1; off>>=1) s += __shfl_xor(s, off);
    if (lane==0) sl[t] = s + cc;
  }
  __syncthreads();
  float mx = -3.0e38f;
  for (int t = tid; t < T_MEL; t += 256) if (t < len) mx = fmaxf(mx, sl[t]);
  #pragma unroll
  for (int off=32; off>=1; off>>=1) mx = fmaxf(mx, __shfl_xor(mx, off));
  if (lane==0) red[wv] = mx;
  __syncthreads();
  mx = fmaxf(fmaxf(red[0],red[1]),fmaxf(red[2],red[3]));
  float se = 0.f;
  for (int t = tid; t < T_MEL; t += 256){
    float p = (t < len) ? __expf(sl[t]-mx) : 0.f;
    sl[t] = p; se += p;
  }
  #pragma unroll
  for (int off=32; off>=1; off>>=1) se += __shfl_xor(se, off);
  if (lane==0) red[4+wv] = se;
  __syncthreads();
  float rsum = 1.f/(red[4]+red[5]+red[6]+red[7]);
  float* sc_out = d_out + 1824 + (b*L_TXT + l)*T_MEL;
  for (int t = tid; t < T_MEL; t += 256){
    float p = sl[t]*rsum;
    sl[t] = p; sc_out[t] = p;
  }
  __syncthreads();
  float a = 0.f;
  int e = tid;
  #pragma unroll 4
  for (int t = 0; t < len; t++) a += sl[t]*x1[t*E + e];
  ws[OFF_H0 + (b*L_TXT+l)*E + e] = q1[e] + a;
}

// ---- gates_in: gathered_in[b,row(t),:] @ WihT + (bih+bhh)
//      output layout: G[dir][t][b][gate*128+unit]  (gate 0:i 1:f 2:g 3:o) ----
__global__ __launch_bounds__(512) void k_gates(const float* __restrict__ in,
                                               const int* __restrict__ txt_len,
                                               float* __restrict__ gates, int layer,
                                               float* __restrict__ ws){
  int idx = blockIdx.x; int tt = idx & 15; int dir = (idx>>4)&1; int b = idx>>5;
  int tid = threadIdx.x;
  __shared__ float si[8][HID];
  int len = txt_len[b];
  for (int i = tid; i < 8*HID; i += 512){
    int r = i >> 8, k = i & 255;
    int t = tt*8 + r;
    int row = dir ? max(0, len-1-t) : t;
    si[r][k] = in[(b*L_TXT + row)*HID + k];
  }
  __syncthreads();
  int ld = layer*2 + dir;
  int g = tid;
  float bsum = ws[OFF_BSUM + ld*512 + g];
  float acc[8];
  #pragma unroll
  for (int r=0;r<8;r++) acc[r] = bsum;
  const float* wt = ws + OFF_WIHT + ld*256*512;
  for (int k=0;k<HID;k++){
    float w = wt[k*512 + g];
    #pragma unroll
    for (int r=0;r<8;r++) acc[r] += si[r][k]*w;
  }
  float* go = gates + (((size_t)(dir*L_TXT + tt*8)*8) + b)*512 + g;
  #pragma unroll
  for (int r=0;r<8;r++) go[(size_t)r*8*512] = acc[r];
}

// ---- recurrent scan v7 (batched MFMA) ; ONE block per dir ; 1024 thr = 16 waves
//      step = Whh[512x128] x H[128x16] (cols = 8 b + 8 pad) via mfma 16x16x32 bf16.
//      waves 0-7: gates (i,f) of units 16w..16w+15 ; waves 8-15: (g,o) same units.
//      8 A-fragments/wave = 32 VGPR (survivable). tg,so exchanged via LDS.
//      h -> bf16 H_lds (double-buffered) + f32 hseq[dir][s][b][u] in global. ----
__global__ __launch_bounds__(1024, 1) void k_scan(const float* __restrict__ G,
                                                  const float* __restrict__ whh_all,
                                                  float* __restrict__ hseq, int layer){
  int dir = blockIdx.x;
  int tid = threadIdx.x;
  int w = tid >> 6, lane = tid & 63;
  int r16 = lane & 15, h4 = lane >> 4;
  int lo = (w < 8) ? 1 : 0;        // lo waves: i,f + own c,h ; hi waves: g,o
  int wm = lo ? w : (w - 8);       // unit group 0..7 (units 16wm..16wm+15)
  __shared__ ushort Hb[2][8][136];            // bf16 h, [buf][b][unit], stride 136
  __shared__ float exch[2][128][17];          // [0]=tanh(g), [1]=sig(o) ; [u][b]

  // A fragments: tiles mA = lo? wm : 16+wm (i|g), mB = lo? 8+wm : 24+wm (f|o)
  int mA = lo ? wm : 16 + wm;
  int mB = lo ? 8 + wm : 24 + wm;
  const float* wb = whh_all + (size_t)(layer*2+dir)*512*HH;
  #define LDA(m,t) ({ const float* rp_ = wb + (size_t)(16*(m) + r16)*HH + 32*(t) + 8*h4; \
      float4 p0_ = *(const float4*)rp_; float4 p1_ = *(const float4*)(rp_+4); \
      short8v f_ = { bf16b(p0_.x),bf16b(p0_.y),bf16b(p0_.z),bf16b(p0_.w), \
                     bf16b(p1_.x),bf16b(p1_.y),bf16b(p1_.z),bf16b(p1_.w) }; f_; })
  short8v A0=LDA(mA,0), A1=LDA(mA,1), A2=LDA(mA,2), A3=LDA(mA,3);
  short8v B0=LDA(mB,0), B1=LDA(mB,1), B2=LDA(mB,2), B3=LDA(mB,3);
  #undef LDA

  // zero both H buffers
  for (int i = tid; i < 2*8*136; i += 1024) ((ushort*)Hb)[i] = 0;

  int u0 = 16*wm + 4*h4;               // 4 consecutive units owned by this lane's C rows
  int bb = (r16 < 8) ? r16 : 7;        // clamp pad columns to b=7 (broadcast)
  const float* gbase = G + (size_t)dir*L_TXT*8*512 + (size_t)bb*512;
  int offA = (lo ? 0   : 256) + u0;    // i | g
  int offB = (lo ? 128 : 384) + u0;    // f | o
  float4 qA = *(const float4*)(gbase + offA);
  float4 qB = *(const float4*)(gbase + offB);
  float c0=0.f, c1=0.f, c2=0.f, c3=0.f;
  __syncthreads();

  for (int s=0; s<L_TXT; s++){
    // B-fragments: lane (r16,h4) needs H[units 32t+8h4..+7][b=r16] ; clamped rows broadcast
    const ushort* hb = &Hb[s&1][bb][8*h4];
    short8v hb0 = *(const short8v*)(hb);
    short8v hb1 = *(const short8v*)(hb+32);
    short8v hb2 = *(const short8v*)(hb+64);
    short8v hb3 = *(const short8v*)(hb+96);
    f32x4 aA = {0.f,0.f,0.f,0.f}, aB = {0.f,0.f,0.f,0.f};
    aA = __builtin_amdgcn_mfma_f32_16x16x32_bf16(A0,hb0,aA,0,0,0);
    aB = __builtin_amdgcn_mfma_f32_16x16x32_bf16(B0,hb0,aB,0,0,0);
    aA = __builtin_amdgcn_mfma_f32_16x16x32_bf16(A1,hb1,aA,0,0,0);
    aB = __builtin_amdgcn_mfma_f32_16x16x32_bf16(B1,hb1,aB,0,0,0);
    aA = __builtin_amdgcn_mfma_f32_16x16x32_bf16(A2,hb2,aA,0,0,0);
    aB = __builtin_amdgcn_mfma_f32_16x16x32_bf16(B2,hb2,aB,0,0,0);
    aA = __builtin_amdgcn_mfma_f32_16x16x32_bf16(A3,hb3,aA,0,0,0);
    aB = __builtin_amdgcn_mfma_f32_16x16x32_bf16(B3,hb3,aB,0,0,0);
    // prefetch next step's gate inputs (consumed next iteration)
    const float* gn = gbase + (size_t)(s+1 < L_TXT ? s+1 : s)*4096;
    float4 nA = *(const float4*)(gn + offA);
    float4 nB = *(const float4*)(gn + offB);
    if (!lo){
      // hi waves: write tanh(g), sigmoid(o) for (u, b=r16)
      #pragma unroll
      for (int r=0;r<4;r++){
        int u = u0 + r;
        exch[0][u][r16] = fast_tanh   (aA[r] + (&qA.x)[r]);
        exch[1][u][r16] = fast_sigmoid(aB[r] + (&qB.x)[r]);
      }
    }
    __syncthreads();
    if (lo){
      float h0v,h1v,h2v,h3v;
      {
        float si_ = fast_sigmoid(aA[0] + qA.x);
        float sf_ = fast_sigmoid(aB[0] + qB.x);
        c0 = sf_*c0 + si_*exch[0][u0+0][r16];
        h0v = exch[1][u0+0][r16]*fast_tanh(c0);
      }{
        float si_ = fast_sigmoid(aA[1] + qA.y);
        float sf_ = fast_sigmoid(aB[1] + qB.y);
        c1 = sf_*c1 + si_*exch[0][u0+1][r16];
        h1v = exch[1][u0+1][r16]*fast_tanh(c1);
      }{
        float si_ = fast_sigmoid(aA[2] + qA.z);
        float sf_ = fast_sigmoid(aB[2] + qB.z);
        c2 = sf_*c2 + si_*exch[0][u0+2][r16];
        h2v = exch[1][u0+2][r16]*fast_tanh(c2);
      }{
        float si_ = fast_sigmoid(aA[3] + qA.w);
        float sf_ = fast_sigmoid(aB[3] + qB.w);
        c3 = sf_*c3 + si_*exch[0][u0+3][r16];
        h3v = exch[1][u0+3][r16]*fast_tanh(c3);
      }
      if (r16 < 8){
        uint lo32 = (uint)(ushort)bf16b(h0v) | ((uint)(ushort)bf16b(h1v) << 16);
        uint hi32 = (uint)(ushort)bf16b(h2v) | ((uint)(ushort)bf16b(h3v) << 16);
        *(uint2*)&Hb[(s+1)&1][r16][u0] = make_uint2(lo32, hi32);
        *(float4*)&hseq[((size_t)(dir*L_TXT+s)*8 + r16)*HH + u0] = make_float4(h0v,h1v,h2v,h3v);
      }
    }
    qA = nA; qB = nB;
    __syncthreads();
  }
}

// ---- pack hseq[dir][s][b][u] -> out[b][pos][dir*128+u] with pack-reverse semantics ----
__global__ __launch_bounds__(256) void k_pack(const float* __restrict__ hseq,
                                              const int* __restrict__ txt_len,
                                              float* __restrict__ out){
  int blk = blockIdx.x;            // b*L + pos
  int b = blk >> 7, pos = blk & 127;
  int tid = threadIdx.x;           // dir*128 + u
  int dir = tid >> 7, u = tid & 127;
  int len = txt_len[b];
  int s = dir ? (pos < len ? len-1-pos : 0) : pos;
  out[(size_t)blk*HID + tid] = hseq[((size_t)(dir*L_TXT+s)*8 + b)*HH + u];
}

// ---- masked mean pool + p1/tanh + normalize + p2 ----
__global__ __launch_bounds__(256) void k_final(const float* __restrict__ o2,
                                               const int* __restrict__ txt_len,
                                               const float* __restrict__ p1w,
                                               const float* __restrict__ p1b,
                                               const float* __restrict__ p2w,
                                               const float* __restrict__ p2b,
                                               float* __restrict__ d_out){
  int b = blockIdx.x; int tid = threadIdx.x;
  __shared__ float pl[HID];
  __shared__ float ol[EMB];
  __shared__ float nrm;
  int len = txt_len[b];
  float s = 0.f;
  for (int t=0; t<len; t++) s += o2[(b*L_TXT+t)*HID + tid];
  pl[tid] = s / (float)len;
  __syncthreads();
  if (tid < EMB){
    float a = p1b[tid];
    for (int k=0;k<HID;k++) a += pl[k]*p1w[tid*HID+k];
    ol[tid] = fast_tanh(a);
  }
  __syncthreads();
  if (tid == 0){
    float q = 0.f;
    for (int k=0;k<EMB;k++) q += ol[k]*ol[k];
    nrm = rsqrtf(q);
  }
  __syncthreads();
  if (tid < EMB) d_out[800 + b*EMB + tid] = ol[tid]*nrm;
  if (tid < N_SPK){
    float a = p2b[tid];
    for (int k=0;k<EMB;k++) a += ol[k]*p2w[tid*EMB+k];
    d_out[b*N_SPK + tid] = a;
  }
}

extern "C" void kernel_launch(void* const* d_in, const int* in_sizes, int n_in,
                              void* d_out, int out_size, void* d_ws, size_t ws_size,
                              hipStream_t stream) {
  const float* x       = (const float*)d_in[0];
  const int*   mel_len = (const int*)  d_in[1];
  const float* text    = (const float*)d_in[2];
  const int*   txt_len = (const int*)  d_in[3];
  const float* Wx      = (const float*)d_in[4];
  const float* bx      = (const float*)d_in[5];
  const float* Wq      = (const float*)d_in[6];
  const float* bq      = (const float*)d_in[7];
  const float* Wout    = (const float*)d_in[8];
  const float* bout    = (const float*)d_in[9];
  const float* v       = (const float*)d_in[10];
  const float* wih     = (const float*)d_in[11];
  const float* whh     = (const float*)d_in[12];
  const float* bih     = (const float*)d_in[13];
  const float* bhh     = (const float*)d_in[14];
  const float* p1w     = (const float*)d_in[15];
  const float* p1b     = (const float*)d_in[16];
  const float* p2w     = (const float*)d_in[17];
  const float* p2b     = (const float*)d_in[18];
  float* ws  = (float*)d_ws;
  float* out = (float*)d_out;

  k_prep<<<1618, 256, 0, stream>>>(Wout, bout, v, Wx, Wq, wih, bih, bhh, ws);
  k_x1  <<<800, 256, 0, stream>>>(x, bx, ws);
  k_q1  <<<256, 256, 0, stream>>>(text, bq, ws);
  k_score<<<1024, 256, 0, stream>>>(mel_len, ws, out);

  float* G = ws + OFF_G;
  k_gates<<<256, 512, 0, stream>>>(ws + OFF_H0, txt_len, G, 0, ws);
  k_scan <<<2, 1024, 0, stream>>>(G, whh, ws + OFF_HS0, 0);
  k_pack <<<1024, 256, 0, stream>>>(ws + OFF_HS0, txt_len, ws + OFF_O1);
  k_gates<<<256, 512, 0, stream>>>(ws + OFF_O1, txt_len, G, 1, ws);
  k_scan <<<2, 1024, 0, stream>>>(G, whh, ws + OFF_HS1, 1);
  k_pack <<<1024, 256, 0, stream>>>(ws + OFF_HS1, txt_len, ws + OFF_O2);

  k_final<<<8, 256, 0, stream>>>(ws + OFF_O2, txt_len, p1w, p1b, p2w, p2b, out);
}

// Round 8
// 582.620 us; speedup vs baseline: 1.6232x; 1.2432x over previous
//
#include <hip/hip_runtime.h>
#include <hip/hip_bf16.h>
#include <math.h>

#define B 8
#define T_MEL 400
#define N_MEL 80
#define L_TXT 128
#define D_TXT 512
#define E 256
#define HID 256
#define EMB 128
#define N_SPK 100
#define HH 128

// ---- workspace layout (float element offsets) ----
#define OFF_W      0
#define OFF_C      256
#define OFF_WXT    272
#define OFF_WQT    (OFF_WXT + N_MEL*E)        // 20752
#define OFF_WIHT   (OFF_WQT + D_TXT*E)        // 151824
#define OFF_BSUM   (OFF_WIHT + 2*2*256*512)   // 676112
#define OFF_X1     (OFF_BSUM + 2048)          // 678160
#define OFF_Q1     (OFF_X1 + B*T_MEL*E)       // 1497360
#define OFF_G      OFF_X1                      // gates overlay x1+q1 (dead by then)
#define OFF_H0     (OFF_Q1 + B*L_TXT*E)       // 1759504
#define OFF_O1     (OFF_H0 + B*L_TXT*E)       // 2021648
#define OFF_O2     (OFF_O1 + B*L_TXT*HID)     // 2283792
#define OFF_HS0    OFF_H0                      // hseq layer0 overlays H0 (dead after k_gates0)
#define OFF_HS1    OFF_O1                      // hseq layer1 overlays O1 (dead after k_gates1)

typedef _Float16 half2v __attribute__((ext_vector_type(2)));

__device__ __forceinline__ float fast_sigmoid(float x){ return 1.f/(1.f+__expf(-x)); }
__device__ __forceinline__ float fast_tanh(float x){ float e=__expf(2.f*x); return 1.f - 2.f/(e+1.f); }

__device__ __forceinline__ float fdot2(uint a, uint b, float c){
  half2v ha = __builtin_bit_cast(half2v, a);
  half2v hb = __builtin_bit_cast(half2v, b);
#if __has_builtin(__builtin_amdgcn_fdot2)
  return __builtin_amdgcn_fdot2(ha, hb, c, false);
#else
  float r;
  asm("v_dot2_f32_f16 %0, %1, %2, %3" : "=v"(r) : "v"(a), "v"(b), "v"(c));
  return r;
#endif
}
__device__ __forceinline__ uint packh2(float a, float b){
  union { _Float16 h[2]; uint u; } x;
  x.h[0] = (_Float16)a; x.h[1] = (_Float16)b; return x.u;
}

// ---- prep: w = Wout^T v, c = bout.v ; transposes WxT, WqT, WihT ; bias sums ----
__global__ void k_prep(const float* __restrict__ Wout, const float* __restrict__ bout,
                       const float* __restrict__ v,    const float* __restrict__ Wx,
                       const float* __restrict__ Wq,   const float* __restrict__ wih,
                       const float* __restrict__ bih,  const float* __restrict__ bhh,
                       float* __restrict__ ws){
  int blk = blockIdx.x, tid = threadIdx.x;
  if (blk == 0){
    float acc = 0.f;
    for (int j=0;j<E;j++) acc += Wout[j*E + tid] * v[j];
    ws[OFF_W + tid] = acc;
    if (tid==0){ float c=0.f; for(int j=0;j<E;j++) c += bout[j]*v[j]; ws[OFF_C]=c; }
  } else if (blk <= N_MEL){
    int m = blk-1;
    ws[OFF_WXT + m*E + tid] = Wx[tid*N_MEL + m];
  } else if (blk <= N_MEL + D_TXT){
    int k = blk-1-N_MEL;
    ws[OFF_WQT + k*E + tid] = Wq[tid*D_TXT + k];
  } else if (blk <= N_MEL + D_TXT + 1024){
    int idx = blk-1-N_MEL-D_TXT;      // ld*256 + k
    int ld = idx >> 8, k = idx & 255;
    for (int g = tid; g < 512; g += 256)
      ws[OFF_WIHT + idx*512 + g] = wih[(ld*512+g)*256 + k];
  } else {
    for (int i = tid; i < 2048; i += 256)
      ws[OFF_BSUM + i] = bih[i] + bhh[i];
  }
}

// ---- x1[b,t,e] = sum_m x[b,m,t]*Wx[e,m] + bx[e] ; t-tile 4 ----
__global__ __launch_bounds__(256) void k_x1(const float* __restrict__ x,
                                            const float* __restrict__ bx,
                                            float* __restrict__ ws){
  int blk = blockIdx.x; int b = blk/100; int t0 = (blk%100)*4; int tid = threadIdx.x;
  __shared__ float sx[N_MEL][4];
  for (int i = tid; i < N_MEL*4; i += 256){
    int m = i>>2, ii = i&3;
    sx[m][ii] = x[(b*N_MEL+m)*T_MEL + t0 + ii];
  }
  __syncthreads();
  float bxe = bx[tid];
  float a0=bxe,a1=bxe,a2=bxe,a3=bxe;
  const float* wxt = ws + OFF_WXT;
  #pragma unroll 4
  for (int m=0;m<N_MEL;m++){
    float w = wxt[m*E + tid];
    a0 += sx[m][0]*w; a1 += sx[m][1]*w; a2 += sx[m][2]*w; a3 += sx[m][3]*w;
  }
  float* x1 = ws + OFF_X1 + (b*T_MEL + t0)*E + tid;
  x1[0]=a0; x1[E]=a1; x1[2*E]=a2; x1[3*E]=a3;
}

// ---- q1[b,l,e] = sum_d text[b,l,d]*Wq[e,d] + bq[e] ; l-tile 4 ----
__global__ __launch_bounds__(256) void k_q1(const float* __restrict__ text,
                                            const float* __restrict__ bq,
                                            float* __restrict__ ws){
  int blk = blockIdx.x; int b = blk/32; int l0 = (blk%32)*4; int tid = threadIdx.x;
  __shared__ float st[4][D_TXT];
  for (int i = tid; i < 4*D_TXT; i += 256){
    int li = i / D_TXT, k = i % D_TXT;
    st[li][k] = text[(b*L_TXT + l0 + li)*D_TXT + k];
  }
  __syncthreads();
  float bqe = bq[tid];
  float a0=bqe,a1=bqe,a2=bqe,a3=bqe;
  const float* wqt = ws + OFF_WQT;
  #pragma unroll 2
  for (int k=0;k<D_TXT;k++){
    float w = wqt[k*E + tid];
    a0 += st[0][k]*w; a1 += st[1][k]*w; a2 += st[2][k]*w; a3 += st[3][k]*w;
  }
  float* q1 = ws + OFF_Q1 + (b*L_TXT + l0)*E + tid;
  q1[0]=a0; q1[E]=a1; q1[2*E]=a2; q1[3*E]=a3;
}

// ---- scores + masked softmax + context + h0 ; one block per (b,l) ----
__global__ __launch_bounds__(256) void k_score(const int* __restrict__ mel_len,
                                               float* __restrict__ ws,
                                               float* __restrict__ d_out){
  int blk = blockIdx.x; int b = blk >> 7; int l = blk & 127;
  int tid = threadIdx.x; int lane = tid & 63; int wv = tid >> 6;
  __shared__ float sl[T_MEL];
  __shared__ float red[8];
  const float* x1 = ws + OFF_X1 + b*T_MEL*E;
  const float* q1 = ws + OFF_Q1 + (b*L_TXT+l)*E;
  float qv[4], wv4[4];
  #pragma unroll
  for (int j=0;j<4;j++){ qv[j] = q1[lane+64*j]; wv4[j] = ws[OFF_W + lane + 64*j]; }
  float cc = ws[OFF_C];
  int len = mel_len[b];
  for (int t = wv; t < T_MEL; t += 4){
    const float* xr = x1 + t*E;
    float s = 0.f;
    #pragma unroll
    for (int j=0;j<4;j++) s += wv4[j]*fast_tanh(xr[lane+64*j] + qv[j]);
    #pragma unroll
    for (int off=32; off>=1; off>>=1) s += __shfl_xor(s, off);
    if (lane==0) sl[t] = s + cc;
  }
  __syncthreads();
  float mx = -3.0e38f;
  for (int t = tid; t < T_MEL; t += 256) if (t < len) mx = fmaxf(mx, sl[t]);
  #pragma unroll
  for (int off=32; off>=1; off>>=1) mx = fmaxf(mx, __shfl_xor(mx, off));
  if (lane==0) red[wv] = mx;
  __syncthreads();
  mx = fmaxf(fmaxf(red[0],red[1]),fmaxf(red[2],red[3]));
  float se = 0.f;
  for (int t = tid; t < T_MEL; t += 256){
    float p = (t < len) ? __expf(sl[t]-mx) : 0.f;
    sl[t] = p; se += p;
  }
  #pragma unroll
  for (int off=32; off>=1; off>>=1) se += __shfl_xor(se, off);
  if (lane==0) red[4+wv] = se;
  __syncthreads();
  float rsum = 1.f/(red[4]+red[5]+red[6]+red[7]);
  float* sc_out = d_out + 1824 + (b*L_TXT + l)*T_MEL;
  for (int t = tid; t < T_MEL; t += 256){
    float p = sl[t]*rsum;
    sl[t] = p; sc_out[t] = p;
  }
  __syncthreads();
  float a = 0.f;
  int e = tid;
  #pragma unroll 4
  for (int t = 0; t < len; t++) a += sl[t]*x1[t*E + e];
  ws[OFF_H0 + (b*L_TXT+l)*E + e] = q1[e] + a;
}

// ---- gates_in: gathered_in[b,row(t),:] @ WihT + (bih+bhh)
//      output layout: G[dir][t][b][gate*128+unit]  (gate 0:i 1:f 2:g 3:o) ----
__global__ __launch_bounds__(512) void k_gates(const float* __restrict__ in,
                                               const int* __restrict__ txt_len,
                                               float* __restrict__ gates, int layer,
                                               float* __restrict__ ws){
  int idx = blockIdx.x; int tt = idx & 15; int dir = (idx>>4)&1; int b = idx>>5;
  int tid = threadIdx.x;
  __shared__ float si[8][HID];
  int len = txt_len[b];
  for (int i = tid; i < 8*HID; i += 512){
    int r = i >> 8, k = i & 255;
    int t = tt*8 + r;
    int row = dir ? max(0, len-1-t) : t;
    si[r][k] = in[(b*L_TXT + row)*HID + k];
  }
  __syncthreads();
  int ld = layer*2 + dir;
  int g = tid;
  float bsum = ws[OFF_BSUM + ld*512 + g];
  float acc[8];
  #pragma unroll
  for (int r=0;r<8;r++) acc[r] = bsum;
  const float* wt = ws + OFF_WIHT + ld*256*512;
  for (int k=0;k<HID;k++){
    float w = wt[k*512 + g];
    #pragma unroll
    for (int r=0;r<8;r++) acc[r] += si[r][k]*w;
  }
  float* go = gates + (((size_t)(dir*L_TXT + tt*8)*8) + b)*512 + g;
  #pragma unroll
  for (int r=0;r<8;r++) go[(size_t)r*8*512] = acc[r];
}

// ---- recurrent scan v8 (LDS-resident f16 weights + v_dot2) ----
// one block per (b,dir); 1024 thr; thread (u=t>>3, gt=(t>>1)&3, half=t&1) owns
// gate-row gt*128+u over half of h. Weights in LDS as packed f16 pairs, 144-B
// stripes (stride 36 uints) -> uniform bank spread for ds_read_b128.
// Per step: 8 b128 weight reads + 32 fdot2; shfl_xor(1) joins halves;
// shfl_xor(2/4/6) gate exchange (R5-verified); 1 barrier/step; h double-buffered
// as half2; h written fire-and-forget to hseq (k_pack applies reversal).
__global__ __launch_bounds__(1024) void k_scan(const float* __restrict__ Gp,
                                               const float* __restrict__ whh_all,
                                               float* __restrict__ hseq, int layer){
  int dir = blockIdx.x & 1; int b = blockIdx.x >> 1;
  int tid = threadIdx.x;
  int l    = tid & 63;
  int u    = tid >> 3;          // 0..127
  int gt   = (tid >> 1) & 3;    // 0:i 1:f 2:g 3:o
  int half = tid & 1;
  int sr   = gt*256 + u*2 + half;   // stripe index 0..1023

  __shared__ uint wlds[1024*36];    // 144 KB: 1024 stripes x 36 uints (32 data + 4 pad)
  __shared__ uint h2buf[2][64];     // rolling h as half2

  // ---- stage weights: row gt*128+u, cols [64*half, 64*half+64) -> f16 pairs ----
  const float* wr = whh_all + ((size_t)(layer*2+dir)*512 + gt*128 + u)*HH + 64*half;
  uint* dst = wlds + sr*36;
  #pragma unroll
  for (int j=0;j<32;j++) dst[j] = packh2(wr[2*j], wr[2*j+1]);
  if (tid < 128) h2buf[tid>>6][tid&63] = 0;

  const float* gb = Gp + ((size_t)(dir*L_TXT)*8 + b)*512 + (gt*128 + u);
  float gi = gb[0];
  float c_reg = 0.f;
  bool isg = (gt==2);
  __syncthreads();

  for (int s=0; s<L_TXT; s++){
    float gnext = gb[(size_t)(s+1 < L_TXT ? s+1 : s)*4096];
    float acc = half ? 0.f : gi;
    const uint4* wp = (const uint4*)(wlds + sr*36);
    const uint4* hp = (const uint4*)(&h2buf[s&1][32*half]);
    #pragma unroll
    for (int j=0;j<8;j++){
      uint4 a = wp[j]; uint4 hh = hp[j];
      acc = fdot2(a.x,hh.x,acc); acc = fdot2(a.y,hh.y,acc);
      acc = fdot2(a.z,hh.z,acc); acc = fdot2(a.w,hh.w,acc);
    }
    acc += __shfl_xor(acc, 1);             // join h-halves
    float xa = isg ? 2.f*acc : acc;        // tanh(a)=2*sig(2a)-1 (one exp)
    float sg = 1.f/(1.f+__expf(-xa));
    float val = isg ? 2.f*sg - 1.f : sg;
    float f_ = __shfl_xor(val, 2);         // on gt=0 lanes: f
    float g_ = __shfl_xor(val, 4);         // on gt=0 lanes: g
    float o_ = __shfl_xor(val, 6);         // on gt=0 lanes: o
    c_reg = f_*c_reg + val*g_;             // valid on gt=0,half=0 lanes (val=i)
    float h = o_*fast_tanh(c_reg);
    float hn = __shfl_xor(h, 8);           // neighbor unit's h
    if ((l&15)==0) h2buf[(s+1)&1][u>>1] = packh2(h, hn);
    if ((l&7)==0)  hseq[((size_t)(dir*L_TXT+s)*B + b)*HH + u] = h;
    gi = gnext;
    __syncthreads();
  }
}

// ---- pack hseq[dir][s][b][u] -> out[b][pos][dir*128+u] with pack-reverse semantics ----
__global__ __launch_bounds__(256) void k_pack(const float* __restrict__ hseq,
                                              const int* __restrict__ txt_len,
                                              float* __restrict__ out){
  int blk = blockIdx.x;            // b*L + pos
  int b = blk >> 7, pos = blk & 127;
  int tid = threadIdx.x;           // dir*128 + u
  int dir = tid >> 7, u = tid & 127;
  int len = txt_len[b];
  int s = dir ? (pos < len ? len-1-pos : 0) : pos;
  out[(size_t)blk*HID + tid] = hseq[((size_t)(dir*L_TXT+s)*8 + b)*HH + u];
}

// ---- masked mean pool + p1/tanh + normalize + p2 ----
__global__ __launch_bounds__(256) void k_final(const float* __restrict__ o2,
                                               const int* __restrict__ txt_len,
                                               const float* __restrict__ p1w,
                                               const float* __restrict__ p1b,
                                               const float* __restrict__ p2w,
                                               const float* __restrict__ p2b,
                                               float* __restrict__ d_out){
  int b = blockIdx.x; int tid = threadIdx.x;
  __shared__ float pl[HID];
  __shared__ float ol[EMB];
  __shared__ float nrm;
  int len = txt_len[b];
  float s = 0.f;
  for (int t=0; t<len; t++) s += o2[(b*L_TXT+t)*HID + tid];
  pl[tid] = s / (float)len;
  __syncthreads();
  if (tid < EMB){
    float a = p1b[tid];
    for (int k=0;k<HID;k++) a += pl[k]*p1w[tid*HID+k];
    ol[tid] = fast_tanh(a);
  }
  __syncthreads();
  if (tid == 0){
    float q = 0.f;
    for (int k=0;k<EMB;k++) q += ol[k]*ol[k];
    nrm = rsqrtf(q);
  }
  __syncthreads();
  if (tid < EMB) d_out[800 + b*EMB + tid] = ol[tid]*nrm;
  if (tid < N_SPK){
    float a = p2b[tid];
    for (int k=0;k<EMB;k++) a += ol[k]*p2w[tid*EMB+k];
    d_out[b*N_SPK + tid] = a;
  }
}

extern "C" void kernel_launch(void* const* d_in, const int* in_sizes, int n_in,
                              void* d_out, int out_size, void* d_ws, size_t ws_size,
                              hipStream_t stream) {
  const float* x       = (const float*)d_in[0];
  const int*   mel_len = (const int*)  d_in[1];
  const float* text    = (const float*)d_in[2];
  const int*   txt_len = (const int*)  d_in[3];
  const float* Wx      = (const float*)d_in[4];
  const float* bx      = (const float*)d_in[5];
  const float* Wq      = (const float*)d_in[6];
  const float* bq      = (const float*)d_in[7];
  const float* Wout    = (const float*)d_in[8];
  const float* bout    = (const float*)d_in[9];
  const float* v       = (const float*)d_in[10];
  const float* wih     = (const float*)d_in[11];
  const float* whh     = (const float*)d_in[12];
  const float* bih     = (const float*)d_in[13];
  const float* bhh     = (const float*)d_in[14];
  const float* p1w     = (const float*)d_in[15];
  const float* p1b     = (const float*)d_in[16];
  const float* p2w     = (const float*)d_in[17];
  const float* p2b     = (const float*)d_in[18];
  float* ws  = (float*)d_ws;
  float* out = (float*)d_out;

  k_prep<<<1618, 256, 0, stream>>>(Wout, bout, v, Wx, Wq, wih, bih, bhh, ws);
  k_x1  <<<800, 256, 0, stream>>>(x, bx, ws);
  k_q1  <<<256, 256, 0, stream>>>(text, bq, ws);
  k_score<<<1024, 256, 0, stream>>>(mel_len, ws, out);

  float* G = ws + OFF_G;
  k_gates<<<256, 512, 0, stream>>>(ws + OFF_H0, txt_len, G, 0, ws);
  k_scan <<<16, 1024, 0, stream>>>(G, whh, ws + OFF_HS0, 0);
  k_pack <<<1024, 256, 0, stream>>>(ws + OFF_HS0, txt_len, ws + OFF_O1);
  k_gates<<<256, 512, 0, stream>>>(ws + OFF_O1, txt_len, G, 1, ws);
  k_scan <<<16, 1024, 0, stream>>>(G, whh, ws + OFF_HS1, 1);
  k_pack <<<1024, 256, 0, stream>>>(ws + OFF_HS1, txt_len, ws + OFF_O2);

  k_final<<<8, 256, 0, stream>>>(ws + OFF_O2, txt_len, p1w, p1b, p2w, p2b, out);
}

// Round 9
// 540.538 us; speedup vs baseline: 1.7495x; 1.0779x over previous
//
#include <hip/hip_runtime.h>
#include <hip/hip_bf16.h>
#include <math.h>

#define B 8
#define T_MEL 400
#define N_MEL 80
#define L_TXT 128
#define D_TXT 512
#define E 256
#define HID 256
#define EMB 128
#define N_SPK 100
#define HH 128

// ---- workspace layout (float element offsets) ----
#define OFF_W      0
#define OFF_C      256
#define OFF_WXT    272
#define OFF_WQT    (OFF_WXT + N_MEL*E)        // 20752
#define OFF_WIHT   (OFF_WQT + D_TXT*E)        // 151824
#define OFF_BSUM   (OFF_WIHT + 2*2*256*512)   // 676112
#define OFF_X1     (OFF_BSUM + 2048)          // 678160
#define OFF_Q1     (OFF_X1 + B*T_MEL*E)       // 1497360
#define OFF_G      OFF_X1                      // gates overlay x1+q1 (dead by then)
#define OFF_H0     (OFF_Q1 + B*L_TXT*E)       // 1759504
#define OFF_O1     (OFF_H0 + B*L_TXT*E)       // 2021648
#define OFF_O2     (OFF_O1 + B*L_TXT*HID)     // 2283792
#define OFF_HS0    OFF_H0                      // hseq layer0 overlays H0 (dead after k_gates0)
#define OFF_HS1    OFF_O1                      // hseq layer1 overlays O1 (dead after k_gates1)

typedef _Float16 half2v __attribute__((ext_vector_type(2)));

__device__ __forceinline__ float fast_sigmoid(float x){ return 1.f/(1.f+__expf(-x)); }
__device__ __forceinline__ float fast_tanh(float x){ float e=__expf(2.f*x); return 1.f - 2.f/(e+1.f); }

__device__ __forceinline__ float fdot2(uint a, uint b, float c){
  half2v ha = __builtin_bit_cast(half2v, a);
  half2v hb = __builtin_bit_cast(half2v, b);
#if __has_builtin(__builtin_amdgcn_fdot2)
  return __builtin_amdgcn_fdot2(ha, hb, c, false);
#else
  float r;
  asm("v_dot2_f32_f16 %0, %1, %2, %3" : "=v"(r) : "v"(a), "v"(b), "v"(c));
  return r;
#endif
}
__device__ __forceinline__ uint packh2(float a, float b){
  union { _Float16 h[2]; uint u; } x;
  x.h[0] = (_Float16)a; x.h[1] = (_Float16)b; return x.u;
}

// ---- prep: w = Wout^T v, c = bout.v ; transposes WxT, WqT, WihT ; bias sums ----
__global__ void k_prep(const float* __restrict__ Wout, const float* __restrict__ bout,
                       const float* __restrict__ v,    const float* __restrict__ Wx,
                       const float* __restrict__ Wq,   const float* __restrict__ wih,
                       const float* __restrict__ bih,  const float* __restrict__ bhh,
                       float* __restrict__ ws){
  int blk = blockIdx.x, tid = threadIdx.x;
  if (blk == 0){
    float acc = 0.f;
    for (int j=0;j<E;j++) acc += Wout[j*E + tid] * v[j];
    ws[OFF_W + tid] = acc;
    if (tid==0){ float c=0.f; for(int j=0;j<E;j++) c += bout[j]*v[j]; ws[OFF_C]=c; }
  } else if (blk <= N_MEL){
    int m = blk-1;
    ws[OFF_WXT + m*E + tid] = Wx[tid*N_MEL + m];
  } else if (blk <= N_MEL + D_TXT){
    int k = blk-1-N_MEL;
    ws[OFF_WQT + k*E + tid] = Wq[tid*D_TXT + k];
  } else if (blk <= N_MEL + D_TXT + 1024){
    int idx = blk-1-N_MEL-D_TXT;      // ld*256 + k
    int ld = idx >> 8, k = idx & 255;
    for (int g = tid; g < 512; g += 256)
      ws[OFF_WIHT + idx*512 + g] = wih[(ld*512+g)*256 + k];
  } else {
    for (int i = tid; i < 2048; i += 256)
      ws[OFF_BSUM + i] = bih[i] + bhh[i];
  }
}

// ---- x1[b,t,e] = sum_m x[b,m,t]*Wx[e,m] + bx[e] ; t-tile 4 ----
__global__ __launch_bounds__(256) void k_x1(const float* __restrict__ x,
                                            const float* __restrict__ bx,
                                            float* __restrict__ ws){
  int blk = blockIdx.x; int b = blk/100; int t0 = (blk%100)*4; int tid = threadIdx.x;
  __shared__ float sx[N_MEL][4];
  for (int i = tid; i < N_MEL*4; i += 256){
    int m = i>>2, ii = i&3;
    sx[m][ii] = x[(b*N_MEL+m)*T_MEL + t0 + ii];
  }
  __syncthreads();
  float bxe = bx[tid];
  float a0=bxe,a1=bxe,a2=bxe,a3=bxe;
  const float* wxt = ws + OFF_WXT;
  #pragma unroll 4
  for (int m=0;m<N_MEL;m++){
    float w = wxt[m*E + tid];
    a0 += sx[m][0]*w; a1 += sx[m][1]*w; a2 += sx[m][2]*w; a3 += sx[m][3]*w;
  }
  float* x1 = ws + OFF_X1 + (b*T_MEL + t0)*E + tid;
  x1[0]=a0; x1[E]=a1; x1[2*E]=a2; x1[3*E]=a3;
}

// ---- q1[b,l,e] = sum_d text[b,l,d]*Wq[e,d] + bq[e] ; l-tile 4 ----
__global__ __launch_bounds__(256) void k_q1(const float* __restrict__ text,
                                            const float* __restrict__ bq,
                                            float* __restrict__ ws){
  int blk = blockIdx.x; int b = blk/32; int l0 = (blk%32)*4; int tid = threadIdx.x;
  __shared__ float st[4][D_TXT];
  for (int i = tid; i < 4*D_TXT; i += 256){
    int li = i / D_TXT, k = i % D_TXT;
    st[li][k] = text[(b*L_TXT + l0 + li)*D_TXT + k];
  }
  __syncthreads();
  float bqe = bq[tid];
  float a0=bqe,a1=bqe,a2=bqe,a3=bqe;
  const float* wqt = ws + OFF_WQT;
  #pragma unroll 2
  for (int k=0;k<D_TXT;k++){
    float w = wqt[k*E + tid];
    a0 += st[0][k]*w; a1 += st[1][k]*w; a2 += st[2][k]*w; a3 += st[3][k]*w;
  }
  float* q1 = ws + OFF_Q1 + (b*L_TXT + l0)*E + tid;
  q1[0]=a0; q1[E]=a1; q1[2*E]=a2; q1[3*E]=a3;
}

// ---- scores + masked softmax + context + h0 ; one block per (b,l) ----
__global__ __launch_bounds__(256) void k_score(const int* __restrict__ mel_len,
                                               float* __restrict__ ws,
                                               float* __restrict__ d_out){
  int blk = blockIdx.x; int b = blk >> 7; int l = blk & 127;
  int tid = threadIdx.x; int lane = tid & 63; int wv = tid >> 6;
  __shared__ float sl[T_MEL];
  __shared__ float red[8];
  const float* x1 = ws + OFF_X1 + b*T_MEL*E;
  const float* q1 = ws + OFF_Q1 + (b*L_TXT+l)*E;
  float qv[4], wv4[4];
  #pragma unroll
  for (int j=0;j<4;j++){ qv[j] = q1[lane+64*j]; wv4[j] = ws[OFF_W + lane + 64*j]; }
  float cc = ws[OFF_C];
  int len = mel_len[b];
  for (int t = wv; t < T_MEL; t += 4){
    const float* xr = x1 + t*E;
    float s = 0.f;
    #pragma unroll
    for (int j=0;j<4;j++) s += wv4[j]*fast_tanh(xr[lane+64*j] + qv[j]);
    #pragma unroll
    for (int off=32; off>=1; off>>=1) s += __shfl_xor(s, off);
    if (lane==0) sl[t] = s + cc;
  }
  __syncthreads();
  float mx = -3.0e38f;
  for (int t = tid; t < T_MEL; t += 256) if (t < len) mx = fmaxf(mx, sl[t]);
  #pragma unroll
  for (int off=32; off>=1; off>>=1) mx = fmaxf(mx, __shfl_xor(mx, off));
  if (lane==0) red[wv] = mx;
  __syncthreads();
  mx = fmaxf(fmaxf(red[0],red[1]),fmaxf(red[2],red[3]));
  float se = 0.f;
  for (int t = tid; t < T_MEL; t += 256){
    float p = (t < len) ? __expf(sl[t]-mx) : 0.f;
    sl[t] = p; se += p;
  }
  #pragma unroll
  for (int off=32; off>=1; off>>=1) se += __shfl_xor(se, off);
  if (lane==0) red[4+wv] = se;
  __syncthreads();
  float rsum = 1.f/(red[4]+red[5]+red[6]+red[7]);
  float* sc_out = d_out + 1824 + (b*L_TXT + l)*T_MEL;
  for (int t = tid; t < T_MEL; t += 256){
    float p = sl[t]*rsum;
    sl[t] = p; sc_out[t] = p;
  }
  __syncthreads();
  float a = 0.f;
  int e = tid;
  #pragma unroll 4
  for (int t = 0; t < len; t++) a += sl[t]*x1[t*E + e];
  ws[OFF_H0 + (b*L_TXT+l)*E + e] = q1[e] + a;
}

// ---- gates_in: gathered_in[b,row(t),:] @ WihT + (bih+bhh)
//      output layout: G[dir][t][b][gate*128+unit]  (gate 0:i 1:f 2:g 3:o) ----
__global__ __launch_bounds__(512) void k_gates(const float* __restrict__ in,
                                               const int* __restrict__ txt_len,
                                               float* __restrict__ gates, int layer,
                                               float* __restrict__ ws){
  int idx = blockIdx.x; int tt = idx & 15; int dir = (idx>>4)&1; int b = idx>>5;
  int tid = threadIdx.x;
  __shared__ float si[8][HID];
  int len = txt_len[b];
  for (int i = tid; i < 8*HID; i += 512){
    int r = i >> 8, k = i & 255;
    int t = tt*8 + r;
    int row = dir ? max(0, len-1-t) : t;
    si[r][k] = in[(b*L_TXT + row)*HID + k];
  }
  __syncthreads();
  int ld = layer*2 + dir;
  int g = tid;
  float bsum = ws[OFF_BSUM + ld*512 + g];
  float acc[8];
  #pragma unroll
  for (int r=0;r<8;r++) acc[r] = bsum;
  const float* wt = ws + OFF_WIHT + ld*256*512;
  for (int k=0;k<HID;k++){
    float w = wt[k*512 + g];
    #pragma unroll
    for (int r=0;r<8;r++) acc[r] += si[r][k]*w;
  }
  float* go = gates + (((size_t)(dir*L_TXT + tt*8)*8) + b)*512 + g;
  #pragma unroll
  for (int r=0;r<8;r++) go[(size_t)r*8*512] = acc[r];
}

// ---- recurrent scan v9 (LDS f16 weights, wave-contiguous conflict-free layout) ----
// one block per (b,dir); 1024 thr; thread (u=t>>3, gt=(t>>1)&3, half=t&1) owns
// gate-row gt*128+u over half of h. Weight layout: wlds[w][j][lane][uint4] so
// at step-phase j, lane l reads base_w + j*1024B + l*16B  -> banks 4l..4l+3,
// ZERO conflicts (was 8-way with the 144B-stripe scheme: 36*8 == 0 mod 32).
// Same compute as v8: 32 fdot2; shfl_xor(1) joins halves; shfl_xor(2/4/6) gate
// exchange; 1 barrier/step; h double-buffered as half2; hseq fire-and-forget.
__global__ __launch_bounds__(1024) void k_scan(const float* __restrict__ Gp,
                                               const float* __restrict__ whh_all,
                                               float* __restrict__ hseq, int layer){
  int dir = blockIdx.x & 1; int b = blockIdx.x >> 1;
  int tid = threadIdx.x;
  int l    = tid & 63;
  int w    = tid >> 6;          // wave 0..15
  int u    = tid >> 3;          // 0..127
  int gt   = (tid >> 1) & 3;    // 0:i 1:f 2:g 3:o
  int half = tid & 1;

  __shared__ uint wlds[32768];      // 128KB: [(w*8+j)*64+l]*4+k
  __shared__ uint h2buf[2][64];     // rolling h as half2

  // ---- stage weights: row gt*128+u, cols [64*half .. +64) as f16 pairs ----
  // thread's j-th uint4 at wlds + w*2048 + j*256 + l*4 holds cols j*8 .. j*8+7
  const float* wr = whh_all + ((size_t)(layer*2+dir)*512 + gt*128 + u)*HH + 64*half;
  #pragma unroll
  for (int j=0;j<8;j++){
    uint4 v;
    v.x = packh2(wr[j*8+0], wr[j*8+1]);
    v.y = packh2(wr[j*8+2], wr[j*8+3]);
    v.z = packh2(wr[j*8+4], wr[j*8+5]);
    v.w = packh2(wr[j*8+6], wr[j*8+7]);
    *(uint4*)(wlds + w*2048 + j*256 + l*4) = v;   // banks 4l..4l+3: conflict-free
  }
  if (tid < 128) h2buf[tid>>6][tid&63] = 0;

  const float* gb = Gp + ((size_t)(dir*L_TXT)*8 + b)*512 + (gt*128 + u);
  float gi = gb[0];
  float c_reg = 0.f;
  bool isg = (gt==2);
  __syncthreads();

  const uint4* wp = (const uint4*)(wlds + w*2048 + l*4);   // stride 64 uint4 per j

  for (int s=0; s<L_TXT; s++){
    float gnext = gb[(size_t)(s+1 < L_TXT ? s+1 : s)*4096];
    float acc = half ? 0.f : gi;
    const uint4* hp = (const uint4*)(&h2buf[s&1][32*half]);
    #pragma unroll
    for (int j=0;j<8;j++){
      uint4 a = wp[j*64]; uint4 hh = hp[j];
      acc = fdot2(a.x,hh.x,acc); acc = fdot2(a.y,hh.y,acc);
      acc = fdot2(a.z,hh.z,acc); acc = fdot2(a.w,hh.w,acc);
    }
    acc += __shfl_xor(acc, 1);             // join h-halves
    float xa = isg ? 2.f*acc : acc;        // tanh(a)=2*sig(2a)-1 (one exp)
    float sg = 1.f/(1.f+__expf(-xa));
    float val = isg ? 2.f*sg - 1.f : sg;
    float f_ = __shfl_xor(val, 2);         // on gt=0 lanes: f
    float g_ = __shfl_xor(val, 4);         // on gt=0 lanes: g
    float o_ = __shfl_xor(val, 6);         // on gt=0 lanes: o
    c_reg = f_*c_reg + val*g_;             // valid on gt=0,half=0 lanes (val=i)
    float h = o_*fast_tanh(c_reg);
    float hn = __shfl_xor(h, 8);           // neighbor unit's h
    if ((l&15)==0) h2buf[(s+1)&1][u>>1] = packh2(h, hn);
    if ((l&7)==0)  hseq[((size_t)(dir*L_TXT+s)*B + b)*HH + u] = h;
    gi = gnext;
    __syncthreads();
  }
}

// ---- pack hseq[dir][s][b][u] -> out[b][pos][dir*128+u] with pack-reverse semantics ----
__global__ __launch_bounds__(256) void k_pack(const float* __restrict__ hseq,
                                              const int* __restrict__ txt_len,
                                              float* __restrict__ out){
  int blk = blockIdx.x;            // b*L + pos
  int b = blk >> 7, pos = blk & 127;
  int tid = threadIdx.x;           // dir*128 + u
  int dir = tid >> 7, u = tid & 127;
  int len = txt_len[b];
  int s = dir ? (pos < len ? len-1-pos : 0) : pos;
  out[(size_t)blk*HID + tid] = hseq[((size_t)(dir*L_TXT+s)*8 + b)*HH + u];
}

// ---- masked mean pool + p1/tanh + normalize + p2 ----
__global__ __launch_bounds__(256) void k_final(const float* __restrict__ o2,
                                               const int* __restrict__ txt_len,
                                               const float* __restrict__ p1w,
                                               const float* __restrict__ p1b,
                                               const float* __restrict__ p2w,
                                               const float* __restrict__ p2b,
                                               float* __restrict__ d_out){
  int b = blockIdx.x; int tid = threadIdx.x;
  __shared__ float pl[HID];
  __shared__ float ol[EMB];
  __shared__ float nrm;
  int len = txt_len[b];
  float s = 0.f;
  for (int t=0; t<len; t++) s += o2[(b*L_TXT+t)*HID + tid];
  pl[tid] = s / (float)len;
  __syncthreads();
  if (tid < EMB){
    float a = p1b[tid];
    for (int k=0;k<HID;k++) a += pl[k]*p1w[tid*HID+k];
    ol[tid] = fast_tanh(a);
  }
  __syncthreads();
  if (tid == 0){
    float q = 0.f;
    for (int k=0;k<EMB;k++) q += ol[k]*ol[k];
    nrm = rsqrtf(q);
  }
  __syncthreads();
  if (tid < EMB) d_out[800 + b*EMB + tid] = ol[tid]*nrm;
  if (tid < N_SPK){
    float a = p2b[tid];
    for (int k=0;k<EMB;k++) a += ol[k]*p2w[tid*EMB+k];
    d_out[b*N_SPK + tid] = a;
  }
}

extern "C" void kernel_launch(void* const* d_in, const int* in_sizes, int n_in,
                              void* d_out, int out_size, void* d_ws, size_t ws_size,
                              hipStream_t stream) {
  const float* x       = (const float*)d_in[0];
  const int*   mel_len = (const int*)  d_in[1];
  const float* text    = (const float*)d_in[2];
  const int*   txt_len = (const int*)  d_in[3];
  const float* Wx      = (const float*)d_in[4];
  const float* bx      = (const float*)d_in[5];
  const float* Wq      = (const float*)d_in[6];
  const float* bq      = (const float*)d_in[7];
  const float* Wout    = (const float*)d_in[8];
  const float* bout    = (const float*)d_in[9];
  const float* v       = (const float*)d_in[10];
  const float* wih     = (const float*)d_in[11];
  const float* whh     = (const float*)d_in[12];
  const float* bih     = (const float*)d_in[13];
  const float* bhh     = (const float*)d_in[14];
  const float* p1w     = (const float*)d_in[15];
  const float* p1b     = (const float*)d_in[16];
  const float* p2w     = (const float*)d_in[17];
  const float* p2b     = (const float*)d_in[18];
  float* ws  = (float*)d_ws;
  float* out = (float*)d_out;

  k_prep<<<1618, 256, 0, stream>>>(Wout, bout, v, Wx, Wq, wih, bih, bhh, ws);
  k_x1  <<<800, 256, 0, stream>>>(x, bx, ws);
  k_q1  <<<256, 256, 0, stream>>>(text, bq, ws);
  k_score<<<1024, 256, 0, stream>>>(mel_len, ws, out);

  float* G = ws + OFF_G;
  k_gates<<<256, 512, 0, stream>>>(ws + OFF_H0, txt_len, G, 0, ws);
  k_scan <<<16, 1024, 0, stream>>>(G, whh, ws + OFF_HS0, 0);
  k_pack <<<1024, 256, 0, stream>>>(ws + OFF_HS0, txt_len, ws + OFF_O1);
  k_gates<<<256, 512, 0, stream>>>(ws + OFF_O1, txt_len, G, 1, ws);
  k_scan <<<16, 1024, 0, stream>>>(G, whh, ws + OFF_HS1, 1);
  k_pack <<<1024, 256, 0, stream>>>(ws + OFF_HS1, txt_len, ws + OFF_O2);

  k_final<<<8, 256, 0, stream>>>(ws + OFF_O2, txt_len, p1w, p1b, p2w, p2b, out);
}